// Round 4
// baseline (137.433 us; speedup 1.0000x reference)
//
#include <hip/hip_runtime.h>
#include <stdint.h>

constexpr int B = 2, H = 256, W = 256, G = 96, C = 12, K = 128;
constexpr int HW = H * W;          // 65536
constexpr int G3 = G * G * G;      // 884736
constexpr float CENTER_THRESHOLD = 0.1f;
constexpr int STUFF_AREA = 2048;
constexpr int LABEL_DIVISOR = 1000;
constexpr float VOXEL_SIZE = 0.0625f;
constexpr float TRUNCATION = 3.0f;
constexpr float TSDF_THRESH = 1.5f;
constexpr float DEPTH_MAX = 6.0f;
constexpr float HALF_EXT = 3.0f;   // G*VOXEL_SIZE/2
constexpr int TOPK_CAP = 6144;     // LDS candidate capacity (48 KB)
constexpr int TOPK_NB = 64;        // blocks per batch for k_topk
constexpr int GEOM_BLOCKS = (B * G3) / 1024;   // 1728
constexpr int PAN2_BLOCKS = (B * HW) / 1024;   // 128

// output layout (floats)
constexpr size_t O_PAN2 = 0;
constexpr size_t O_PAN3 = 131072;
constexpr size_t O_GEOM = 1900544;
constexpr size_t O_CENT = 3670016;
constexpr size_t O_CLS  = 3670528;
constexpr size_t O_SCR  = 3670784;

// ws layout (bytes)
constexpr size_t WS_CY   = 256;
constexpr size_t WS_CX   = 1280;
constexpr size_t WS_SC   = 2304;
constexpr size_t WS_CL   = 3328;
constexpr size_t WS_SEM2 = 4352;
constexpr size_t WS_NMS  = 135424;
constexpr size_t WS_CV   = 266496;
constexpr size_t WS_CI   = 790784;
constexpr size_t WS_SEM3 = 1315072;

typedef float f32x2 __attribute__((ext_vector_type(2)));

// Packed fp32 ops (VOP3P, 2 floats per VGPR pair). IEEE-identical to scalar
// v_add_f32/v_mul_f32 per element -> bit-exact vs the scalar reference.
__device__ inline f32x2 pk_add(f32x2 a, f32x2 b) {
    f32x2 d;
    asm("v_pk_add_f32 %0, %1, %2" : "=v"(d) : "v"(a), "v"(b));
    return d;
}
__device__ inline f32x2 pk_mul(f32x2 a, f32x2 b) {
    f32x2 d;
    asm("v_pk_mul_f32 %0, %1, %2" : "=v"(d) : "v"(a), "v"(b));
    return d;
}

// One block per image row: separable clamped-window 7x7 max.
__global__ void k_pre2d(const float* __restrict__ sem2in,
                        const float* __restrict__ center2d,
                        uint8_t* __restrict__ semMap, uint8_t* __restrict__ nmsMask,
                        float* __restrict__ candVal, int* __restrict__ candIdx,
                        int* __restrict__ candCount, int* __restrict__ counts2d) {
    __shared__ float vmax[W];
    __shared__ int lcnt[C];
    int t = threadIdx.x;               // w
    int rb = blockIdx.x;               // b*H + h
    int b = rb / H, h = rb % H;
    if (t < C) lcnt[t] = 0;
    const float* hmb = center2d + (size_t)b * HW;
    int h0 = max(h - 3, 0), h1 = min(h + 3, H - 1);
    float m = -INFINITY;
    for (int y = h0; y <= h1; ++y) m = fmaxf(m, hmb[y * W + t]);
    vmax[t] = m;
    __syncthreads();
    int w0 = max(t - 3, 0), w1 = min(t + 3, W - 1);
    float mm = -INFINITY;
    for (int x = w0; x <= w1; ++x) mm = fmaxf(mm, vmax[x]);
    int p = h * W + t;
    float hm = hmb[p];
    // semantic argmax (first max wins, matches jnp.argmax)
    const float* s = sem2in + (size_t)b * C * HW + p;
    float best = s[0]; int cls = 0;
#pragma unroll
    for (int c = 1; c < C; ++c) {
        float v = s[(size_t)c * HW];
        if (v > best) { best = v; cls = c; }
    }
    int gid = b * HW + p;
    semMap[gid] = (uint8_t)cls;
    atomicAdd(&lcnt[cls], 1);
    bool cand = (hm == mm);
    nmsMask[gid] = cand ? 1 : 0;
    if (cand) {
        int pos = atomicAdd(&candCount[b], 1);
        if (pos < HW) {
            candVal[(size_t)b * HW + pos] = hm;
            candIdx[(size_t)b * HW + pos] = p;
        }
    }
    __syncthreads();
    if (t < C) atomicAdd(&counts2d[b * C + t], lcnt[t]);
}

// Wave-per-candidate exact top-k (rank scatter; order-invariant).
__global__ __launch_bounds__(256)
void k_topk(const uint8_t* __restrict__ semMap, const uint8_t* __restrict__ nmsMask,
            const float* __restrict__ candVal, const int* __restrict__ candIdx,
            const int* __restrict__ candCount,
            float* __restrict__ cyA, float* __restrict__ cxA,
            float* __restrict__ scA, int* __restrict__ clA,
            float* __restrict__ out) {
    __shared__ float2 cd[TOPK_CAP];
    int b = blockIdx.x / TOPK_NB;
    int sub = blockIdx.x % TOPK_NB;
    int t = threadIdx.x;
    int lane = t & 63;
    int wv = sub * 4 + (t >> 6);
    int n = candCount[b];
    if (n > HW) n = HW;
    const float* cv = candVal + (size_t)b * HW;
    const int*  ci = candIdx + (size_t)b * HW;
    bool useLds = (n <= TOPK_CAP);
    if (useLds) {
        for (int i = t; i < n; i += 256)
            cd[i] = make_float2(cv[i], __int_as_float(ci[i]));
    }
    __syncthreads();
    for (int i = wv; i < n; i += TOPK_NB * 4) {
        float v; int id;
        if (useLds) { float2 c = cd[i]; v = c.x; id = __float_as_int(c.y); }
        else        { v = cv[i]; id = ci[i]; }
        int r = 0;
        if (useLds) {
            for (int j = lane; j < n; j += 64) {
                float2 c = cd[j];
                r += (c.x > v) || (c.x == v && __float_as_int(c.y) < id);
            }
        } else {
            for (int j = lane; j < n; j += 64) {
                float vj = cv[j]; int ij = ci[j];
                r += (vj > v) || (vj == v && ij < id);
            }
        }
#pragma unroll
        for (int off = 32; off >= 1; off >>= 1) r += __shfl_xor(r, off, 64);
        if (lane == 0 && r < K) {
            int o = b * K + r;
            float fy = (float)(id / W);
            float fx = (float)(id % W);
            int cls = (int)semMap[(size_t)b * HW + id];
            cyA[o] = fy; cxA[o] = fx; scA[o] = v; clA[o] = cls;
            out[O_CENT + (size_t)o * 2 + 0] = fy;
            out[O_CENT + (size_t)o * 2 + 1] = fx;
            out[O_CLS + o] = (float)cls;
            out[O_SCR + o] = v;
        }
    }
    if (sub == 0 && t == 0 && n < K) {
        int r = n;
        for (int p = 0; p < HW && r < K; ++p) {
            if (!nmsMask[(size_t)b * HW + p]) {
                int o = b * K + r;
                float fy = (float)(p / W);
                float fx = (float)(p % W);
                int cls = (int)semMap[(size_t)b * HW + p];
                cyA[o] = fy; cxA[o] = fx; scA[o] = 0.0f; clA[o] = cls;
                out[O_CENT + (size_t)o * 2 + 0] = fy;
                out[O_CENT + (size_t)o * 2 + 1] = fx;
                out[O_CLS + o] = (float)cls;
                out[O_SCR + o] = 0.0f;
                ++r;
            }
        }
    }
}

// Fused: geom3d work (blocks [0,GEOM_BLOCKS)) + pan2d work (rest).
// Both depend only on pre2d/topk outputs; pan2d VALU overlaps geom3d HBM.
__global__ void k_mid(const float* __restrict__ geom, const float* __restrict__ occ,
                      const float* __restrict__ sem3in,
                      uint8_t* __restrict__ sem3Map, int* __restrict__ counts3d,
                      const float* __restrict__ offset2d,
                      const uint8_t* __restrict__ semMap,
                      const float* __restrict__ cyA, const float* __restrict__ cxA,
                      const float* __restrict__ scA, const int* __restrict__ clA,
                      const int* __restrict__ counts2d,
                      float* __restrict__ out) {
#pragma clang fp contract(off)
    __shared__ int lcnt[C];
    __shared__ float4 cc4[K];
    __shared__ int clsL[K];
    __shared__ int cntL[C];
    __shared__ int anyV;
    int t = threadIdx.x;
    if (blockIdx.x < GEOM_BLOCKS) {
        // ---- geom3d: truncation write, 3D argmax, fg class counts ----
        if (t < C) lcnt[t] = 0;
        __syncthreads();
        int base = (blockIdx.x * 256 + t) * 4;
        int b = base / G3, v = base % G3;
        float4 g = *(const float4*)(geom + base);
        float4 o = *(const float4*)(occ + base);
        float4 go;
        go.x = (o.x <= 0.0f) ? TRUNCATION : g.x;
        go.y = (o.y <= 0.0f) ? TRUNCATION : g.y;
        go.z = (o.z <= 0.0f) ? TRUNCATION : g.z;
        go.w = (o.w <= 0.0f) ? TRUNCATION : g.w;
        *(float4*)(out + O_GEOM + base) = go;
        const float* s = sem3in + (size_t)b * C * G3 + v;
        float4 s0 = *(const float4*)s;
        float bv[4] = {s0.x, s0.y, s0.z, s0.w};
        int bc[4] = {0, 0, 0, 0};
#pragma unroll
        for (int c = 1; c < C; ++c) {
            float4 x = *(const float4*)(s + (size_t)c * G3);
            float xa[4] = {x.x, x.y, x.z, x.w};
#pragma unroll
            for (int q = 0; q < 4; ++q)
                if (xa[q] > bv[q]) { bv[q] = xa[q]; bc[q] = c; }
        }
        *(uchar4*)(sem3Map + base) =
            make_uchar4((uint8_t)bc[0], (uint8_t)bc[1], (uint8_t)bc[2], (uint8_t)bc[3]);
        float ga[4] = {go.x, go.y, go.z, go.w};
#pragma unroll
        for (int q = 0; q < 4; ++q)
            if (fabsf(ga[q]) < TSDF_THRESH) atomicAdd(&lcnt[bc[q]], 1);
        __syncthreads();
        if (t < C) atomicAdd(&counts3d[b * C + t], lcnt[t]);
    } else {
        // ---- pan2d: 4 pixels/thread, packed-fp32 distance argmin ----
        int base = ((blockIdx.x - GEOM_BLOCKS) * 256 + t) * 4;
        int b = base / HW, p = base % HW;
        if (t < K) {
            float sc = scA[b * K + t];
            bool val = sc > CENTER_THRESHOLD;
            float ny = val ? -cyA[b * K + t] : -INFINITY;
            float nx = val ? -cxA[b * K + t] : -INFINITY;
            cc4[t] = make_float4(ny, ny, nx, nx);
            clsL[t] = clA[b * K + t];
        }
        if (t < C) cntL[t] = counts2d[b * C + t];
        if (t == 0) anyV = (scA[b * K] > CENTER_THRESHOLD) ? 1 : 0;
        __syncthreads();
        int h = p / W, w = p % W;
        const float* offb = offset2d + (size_t)b * 2 * HW + p;
        float4 oy = *(const float4*)offb;
        float4 ox = *(const float4*)(offb + HW);
        f32x2 py2[2], px2[2];
        py2[0][0] = (float)h + oy.x;  py2[0][1] = (float)h + oy.y;
        py2[1][0] = (float)h + oy.z;  py2[1][1] = (float)h + oy.w;
        px2[0][0] = (float)(w + 0) + ox.x;  px2[0][1] = (float)(w + 1) + ox.y;
        px2[1][0] = (float)(w + 2) + ox.z;  px2[1][1] = (float)(w + 3) + ox.w;
        float bd[4] = {INFINITY, INFINITY, INFINITY, INFINITY};
        int bi[4] = {0, 0, 0, 0};
#pragma unroll 4
        for (int k = 0; k < K; ++k) {
            float4 c = cc4[k];
            f32x2 ncy; ncy[0] = c.x; ncy[1] = c.y;
            f32x2 ncx; ncx[0] = c.z; ncx[1] = c.w;
#pragma unroll
            for (int pr = 0; pr < 2; ++pr) {
                f32x2 dy = pk_add(py2[pr], ncy);
                f32x2 dx = pk_add(px2[pr], ncx);
                f32x2 d  = pk_add(pk_mul(dy, dy), pk_mul(dx, dx));
                if (d[0] < bd[2 * pr])     { bd[2 * pr] = d[0];     bi[2 * pr] = k; }
                if (d[1] < bd[2 * pr + 1]) { bd[2 * pr + 1] = d[1]; bi[2 * pr + 1] = k; }
            }
        }
        uchar4 s4 = *(const uchar4*)(semMap + base);
        int sa[4] = {s4.x, s4.y, s4.z, s4.w};
        float pout[4];
#pragma unroll
        for (int q = 0; q < 4; ++q) {
            int sem = sa[q];
            int pan;
            if (sem >= 1 && sem <= 7) {
                pan = anyV ? (clsL[bi[q]] * LABEL_DIVISOR + bi[q] + 1) : 0;
            } else {
                pan = (cntL[sem] >= STUFF_AREA) ? sem * LABEL_DIVISOR : 0;
            }
            pout[q] = (float)pan;
        }
        *(float4*)(out + O_PAN2 + base) = make_float4(pout[0], pout[1], pout[2], pout[3]);
    }
}

// 8 voxels/thread, packed-fp32 distance argmin.
__global__ __launch_bounds__(256)
void k_pan3d(const float* __restrict__ off3,
             const uint8_t* __restrict__ sem3Map,
             const float* __restrict__ cyA, const float* __restrict__ cxA,
             const float* __restrict__ scA, const int* __restrict__ clA,
             const int* __restrict__ counts3d,
             const float* __restrict__ intr,
             const float* __restrict__ geomOut,
             float* __restrict__ out) {
#pragma clang fp contract(off)
    __shared__ float4 cc4[K];
    __shared__ int clsL[K];
    __shared__ int cntL[C];
    __shared__ int anyV;
    __shared__ float fxS, fyS, u0S, v0S;
    int t = threadIdx.x;
    int base = (blockIdx.x * 256 + t) * 8;
    int b = base / G3, v = base % G3;
    if (t < K) {
        float sc = scA[b * K + t];
        bool val = sc > CENTER_THRESHOLD;
        float ny = val ? -cyA[b * K + t] : -INFINITY;
        float nx = val ? -cxA[b * K + t] : -INFINITY;
        cc4[t] = make_float4(ny, ny, nx, nx);
        clsL[t] = clA[b * K + t];
    }
    if (t < C) cntL[t] = counts3d[b * C + t];
    if (t == 0) {
        anyV = (scA[b * K] > CENTER_THRESHOLD) ? 1 : 0;
        fxS = intr[(size_t)b * 9 + 0];
        fyS = intr[(size_t)b * 9 + 4];
        u0S = intr[(size_t)b * 9 + 2];
        v0S = intr[(size_t)b * 9 + 5];
    }
    __syncthreads();
    int i = v / (G * G);
    int rem = v % (G * G);
    int j = rem / G;
    int k0 = rem % G;                 // k0..k0+7 same row (G%8==0)
    const float* ob = off3 + (size_t)b * 3 * G3 + v;
    float4 o0a = *(const float4*)ob;
    float4 o0b = *(const float4*)(ob + 4);
    float4 o1a = *(const float4*)(ob + G3);
    float4 o1b = *(const float4*)(ob + G3 + 4);
    float4 o2a = *(const float4*)(ob + 2 * (size_t)G3);
    float4 o2b = *(const float4*)(ob + 2 * (size_t)G3 + 4);
    float oa0[8] = {o0a.x, o0a.y, o0a.z, o0a.w, o0b.x, o0b.y, o0b.z, o0b.w};
    float oa1[8] = {o1a.x, o1a.y, o1a.z, o1a.w, o1b.x, o1b.y, o1b.z, o1b.w};
    float oa2[8] = {o2a.x, o2a.y, o2a.z, o2a.w, o2b.x, o2b.y, o2b.z, o2b.w};
    float fx = fxS, fy = fyS, u0 = u0S, v0 = v0S;
    float uu[8], vv[8];
#pragma unroll
    for (int q = 0; q < 8; ++q) {
        float Xm = ((float)i + oa0[q] + 0.5f) * VOXEL_SIZE - HALF_EXT;
        float Ym = ((float)j + oa1[q] + 0.5f) * VOXEL_SIZE - HALF_EXT;
        float Zr = 0.0f + ((float)(k0 + q) + oa2[q] + 0.5f) * VOXEL_SIZE;
        float Zm = fminf(fmaxf(Zr, 0.1f), DEPTH_MAX);
        uu[q] = fx * Xm / Zm + u0;
        vv[q] = fy * Ym / Zm + v0;
    }
    f32x2 vv2[4], uu2[4];
#pragma unroll
    for (int pr = 0; pr < 4; ++pr) {
        vv2[pr][0] = vv[2 * pr]; vv2[pr][1] = vv[2 * pr + 1];
        uu2[pr][0] = uu[2 * pr]; uu2[pr][1] = uu[2 * pr + 1];
    }
    float bd[8] = {INFINITY, INFINITY, INFINITY, INFINITY,
                   INFINITY, INFINITY, INFINITY, INFINITY};
    int bi[8] = {0, 0, 0, 0, 0, 0, 0, 0};
#pragma unroll 4
    for (int k = 0; k < K; ++k) {
        float4 c = cc4[k];
        f32x2 ncy; ncy[0] = c.x; ncy[1] = c.y;
        f32x2 ncx; ncx[0] = c.z; ncx[1] = c.w;
#pragma unroll
        for (int pr = 0; pr < 4; ++pr) {
            f32x2 dv = pk_add(vv2[pr], ncy);
            f32x2 du = pk_add(uu2[pr], ncx);
            f32x2 d  = pk_add(pk_mul(dv, dv), pk_mul(du, du));
            if (d[0] < bd[2 * pr])     { bd[2 * pr] = d[0];     bi[2 * pr] = k; }
            if (d[1] < bd[2 * pr + 1]) { bd[2 * pr + 1] = d[1]; bi[2 * pr + 1] = k; }
        }
    }
    // epilogue: 8 outputs
    uchar4 sA = *(const uchar4*)(sem3Map + base);
    uchar4 sB = *(const uchar4*)(sem3Map + base + 4);
    int sa[8] = {sA.x, sA.y, sA.z, sA.w, sB.x, sB.y, sB.z, sB.w};
    float4 gA = *(const float4*)(geomOut + base);
    float4 gB = *(const float4*)(geomOut + base + 4);
    float ga[8] = {gA.x, gA.y, gA.z, gA.w, gB.x, gB.y, gB.z, gB.w};
    float pout[8];
#pragma unroll
    for (int q = 0; q < 8; ++q) {
        int sem = sa[q];
        int pan;
        if (sem >= 1 && sem <= 7) {
            pan = anyV ? (clsL[bi[q]] * LABEL_DIVISOR + bi[q] + 1) : 0;
        } else {
            pan = (cntL[sem] >= STUFF_AREA) ? sem * LABEL_DIVISOR : 0;
        }
        pout[q] = (fabsf(ga[q]) < TSDF_THRESH) ? (float)pan : 0.0f;
    }
    *(float4*)(out + O_PAN3 + base) = make_float4(pout[0], pout[1], pout[2], pout[3]);
    *(float4*)(out + O_PAN3 + base + 4) = make_float4(pout[4], pout[5], pout[6], pout[7]);
}

extern "C" void kernel_launch(void* const* d_in, const int* in_sizes, int n_in,
                              void* d_out, int out_size, void* d_ws, size_t ws_size,
                              hipStream_t stream) {
    const float* semantic2d  = (const float*)d_in[0];
    const float* center2d    = (const float*)d_in[1];
    const float* offset2d    = (const float*)d_in[2];
    const float* geometry    = (const float*)d_in[3];
    const float* occupancy3d = (const float*)d_in[4];
    const float* semantic3d  = (const float*)d_in[5];
    const float* offset3d    = (const float*)d_in[6];
    const float* intrinsic   = (const float*)d_in[7];
    float* out = (float*)d_out;
    char* ws = (char*)d_ws;

    int* candCount = (int*)(ws + 0);      // [B]
    int* counts2d  = (int*)(ws + 16);     // [B*C]
    int* counts3d  = (int*)(ws + 112);    // [B*C]
    float* cyA = (float*)(ws + WS_CY);
    float* cxA = (float*)(ws + WS_CX);
    float* scA = (float*)(ws + WS_SC);
    int*   clA = (int*)(ws + WS_CL);
    uint8_t* semMap  = (uint8_t*)(ws + WS_SEM2);
    uint8_t* nmsMask = (uint8_t*)(ws + WS_NMS);
    float* candVal = (float*)(ws + WS_CV);
    int*   candIdx = (int*)(ws + WS_CI);
    uint8_t* sem3Map = (uint8_t*)(ws + WS_SEM3);

    hipMemsetAsync(d_ws, 0, 256, stream);

    k_pre2d<<<B * H, 256, 0, stream>>>(semantic2d, center2d, semMap, nmsMask,
                                       candVal, candIdx, candCount, counts2d);
    k_topk<<<B * TOPK_NB, 256, 0, stream>>>(semMap, nmsMask, candVal, candIdx, candCount,
                                            cyA, cxA, scA, clA, out);
    k_mid<<<GEOM_BLOCKS + PAN2_BLOCKS, 256, 0, stream>>>(
        geometry, occupancy3d, semantic3d, sem3Map, counts3d,
        offset2d, semMap, cyA, cxA, scA, clA, counts2d, out);
    k_pan3d<<<(B * G3) / 2048, 256, 0, stream>>>(offset3d, sem3Map, cyA, cxA, scA, clA,
                                                 counts3d, intrinsic, out + O_GEOM, out);
}

// Round 5
// 108.153 us; speedup vs baseline: 1.2707x; 1.2707x over previous
//
#include <hip/hip_runtime.h>
#include <stdint.h>

constexpr int B = 2, H = 256, W = 256, G = 96, C = 12, K = 128;
constexpr int HW = H * W;          // 65536
constexpr int G3 = G * G * G;      // 884736
constexpr float CENTER_THRESHOLD = 0.1f;
constexpr int STUFF_AREA = 2048;
constexpr int LABEL_DIVISOR = 1000;
constexpr float VOXEL_SIZE = 0.0625f;
constexpr float TRUNCATION = 3.0f;
constexpr float TSDF_THRESH = 1.5f;
constexpr float DEPTH_MAX = 6.0f;
constexpr float HALF_EXT = 3.0f;   // G*VOXEL_SIZE/2
constexpr int TOPK_CAP = 6144;     // LDS candidate capacity (48 KB)
constexpr int TOPK_NB = 64;        // blocks per batch for k_topk
constexpr int PAN2_BLOCKS = (B * HW) / 1024;   // 128
constexpr int F3D_BLOCKS = (B * G3) / 1024;    // 1728

// output layout (floats)
constexpr size_t O_PAN2 = 0;
constexpr size_t O_PAN3 = 131072;
constexpr size_t O_GEOM = 1900544;
constexpr size_t O_CENT = 3670016;
constexpr size_t O_CLS  = 3670528;
constexpr size_t O_SCR  = 3670784;

// ws layout (bytes)
constexpr size_t WS_CY   = 256;
constexpr size_t WS_CX   = 1280;
constexpr size_t WS_SC   = 2304;
constexpr size_t WS_CL   = 3328;
constexpr size_t WS_SEM2 = 4352;
constexpr size_t WS_NMS  = 135424;
constexpr size_t WS_CV   = 266496;
constexpr size_t WS_CI   = 790784;
constexpr size_t WS_SEM3 = 1315072;
constexpr size_t WS_CYV  = 3084544;   // WS_SEM3 + B*G3
constexpr size_t WS_CXV  = 3085568;

// One block per image row: separable clamped-window 7x7 max.
__global__ void k_pre2d(const float* __restrict__ sem2in,
                        const float* __restrict__ center2d,
                        uint8_t* __restrict__ semMap, uint8_t* __restrict__ nmsMask,
                        float* __restrict__ candVal, int* __restrict__ candIdx,
                        int* __restrict__ candCount, int* __restrict__ counts2d) {
    __shared__ float vmax[W];
    __shared__ int lcnt[C];
    int t = threadIdx.x;               // w
    int rb = blockIdx.x;               // b*H + h
    int b = rb / H, h = rb % H;
    if (t < C) lcnt[t] = 0;
    const float* hmb = center2d + (size_t)b * HW;
    int h0 = max(h - 3, 0), h1 = min(h + 3, H - 1);
    float m = -INFINITY;
    for (int y = h0; y <= h1; ++y) m = fmaxf(m, hmb[y * W + t]);
    vmax[t] = m;
    __syncthreads();
    int w0 = max(t - 3, 0), w1 = min(t + 3, W - 1);
    float mm = -INFINITY;
    for (int x = w0; x <= w1; ++x) mm = fmaxf(mm, vmax[x]);
    int p = h * W + t;
    float hm = hmb[p];
    // semantic argmax (first max wins, matches jnp.argmax)
    const float* s = sem2in + (size_t)b * C * HW + p;
    float best = s[0]; int cls = 0;
#pragma unroll
    for (int c = 1; c < C; ++c) {
        float v = s[(size_t)c * HW];
        if (v > best) { best = v; cls = c; }
    }
    int gid = b * HW + p;
    semMap[gid] = (uint8_t)cls;
    atomicAdd(&lcnt[cls], 1);
    bool cand = (hm == mm);
    nmsMask[gid] = cand ? 1 : 0;
    if (cand) {
        int pos = atomicAdd(&candCount[b], 1);
        if (pos < HW) {
            candVal[(size_t)b * HW + pos] = hm;
            candIdx[(size_t)b * HW + pos] = p;
        }
    }
    __syncthreads();
    if (t < C) atomicAdd(&counts2d[b * C + t], lcnt[t]);
}

// Wave-per-candidate exact top-k (rank scatter; order-invariant).
// Also emits cyV/cxV = valid ? center : +INF for the argmin kernels.
__global__ __launch_bounds__(256)
void k_topk(const uint8_t* __restrict__ semMap, const uint8_t* __restrict__ nmsMask,
            const float* __restrict__ candVal, const int* __restrict__ candIdx,
            const int* __restrict__ candCount,
            float* __restrict__ cyA, float* __restrict__ cxA,
            float* __restrict__ scA, int* __restrict__ clA,
            float* __restrict__ cyV, float* __restrict__ cxV,
            float* __restrict__ out) {
    __shared__ float2 cd[TOPK_CAP];
    int b = blockIdx.x / TOPK_NB;
    int sub = blockIdx.x % TOPK_NB;
    int t = threadIdx.x;
    int lane = t & 63;
    int wv = sub * 4 + (t >> 6);
    int n = candCount[b];
    if (n > HW) n = HW;
    const float* cv = candVal + (size_t)b * HW;
    const int*  ci = candIdx + (size_t)b * HW;
    bool useLds = (n <= TOPK_CAP);
    if (useLds) {
        for (int i = t; i < n; i += 256)
            cd[i] = make_float2(cv[i], __int_as_float(ci[i]));
    }
    __syncthreads();
    for (int i = wv; i < n; i += TOPK_NB * 4) {
        float v; int id;
        if (useLds) { float2 c = cd[i]; v = c.x; id = __float_as_int(c.y); }
        else        { v = cv[i]; id = ci[i]; }
        int r = 0;
        if (useLds) {
            for (int j = lane; j < n; j += 64) {
                float2 c = cd[j];
                r += (c.x > v) || (c.x == v && __float_as_int(c.y) < id);
            }
        } else {
            for (int j = lane; j < n; j += 64) {
                float vj = cv[j]; int ij = ci[j];
                r += (vj > v) || (vj == v && ij < id);
            }
        }
#pragma unroll
        for (int off = 32; off >= 1; off >>= 1) r += __shfl_xor(r, off, 64);
        if (lane == 0 && r < K) {
            int o = b * K + r;
            float fy = (float)(id / W);
            float fx = (float)(id % W);
            int cls = (int)semMap[(size_t)b * HW + id];
            bool val = v > CENTER_THRESHOLD;
            cyA[o] = fy; cxA[o] = fx; scA[o] = v; clA[o] = cls;
            cyV[o] = val ? fy : INFINITY;
            cxV[o] = val ? fx : INFINITY;
            out[O_CENT + (size_t)o * 2 + 0] = fy;
            out[O_CENT + (size_t)o * 2 + 1] = fx;
            out[O_CLS + o] = (float)cls;
            out[O_SCR + o] = v;
        }
    }
    if (sub == 0 && t == 0 && n < K) {
        int r = n;
        for (int p = 0; p < HW && r < K; ++p) {
            if (!nmsMask[(size_t)b * HW + p]) {
                int o = b * K + r;
                float fy = (float)(p / W);
                float fx = (float)(p % W);
                int cls = (int)semMap[(size_t)b * HW + p];
                cyA[o] = fy; cxA[o] = fx; scA[o] = 0.0f; clA[o] = cls;
                cyV[o] = INFINITY;
                cxV[o] = INFINITY;
                out[O_CENT + (size_t)o * 2 + 0] = fy;
                out[O_CENT + (size_t)o * 2 + 1] = fx;
                out[O_CLS + o] = (float)cls;
                out[O_SCR + o] = 0.0f;
                ++r;
            }
        }
    }
}

// Fused: pan2d blocks [0,PAN2_BLOCKS) + {geom3d+pan3d} blocks (rest).
// 3D: per-block voxels get truncation/argmax/fg in registers, then the
// 128-center argmin immediately — memory stream overlaps VALU loop.
// Stuff voxels (need global counts3d) are written 0 here, filled by k_stuff.
__global__ __launch_bounds__(256)
void k_fuse(const float* __restrict__ geom, const float* __restrict__ occ,
            const float* __restrict__ sem3in,
            uint8_t* __restrict__ sem3Map, int* __restrict__ counts3d,
            const float* __restrict__ offset2d,
            const uint8_t* __restrict__ semMap,
            const int* __restrict__ counts2d,
            const float* __restrict__ off3,
            const float* __restrict__ intr,
            const float* __restrict__ scA, const int* __restrict__ clA,
            const float* __restrict__ cyV, const float* __restrict__ cxV,
            float* __restrict__ out) {
#pragma clang fp contract(off)
    __shared__ int clsL[K];
    __shared__ int lcnt[C];
    __shared__ int cntL[C];
    int t = threadIdx.x;
    if (blockIdx.x < PAN2_BLOCKS) {
        // ---- pan2d: 4 pixels/thread ----
        int b = blockIdx.x / (PAN2_BLOCKS / B);          // uniform
        int base = blockIdx.x * 1024 + t * 4;
        int p = base - b * HW;
        if (t < K) clsL[t] = clA[b * K + t];
        if (t < C) cntL[t] = counts2d[b * C + t];
        __syncthreads();
        bool anyV = scA[b * K] > CENTER_THRESHOLD;       // uniform
        const float* cyb = cyV + b * K;                  // uniform base
        const float* cxb = cxV + b * K;
        int h = p / W, w = p % W;
        const float* offb = offset2d + (size_t)b * 2 * HW + p;
        float4 oy = *(const float4*)offb;
        float4 ox = *(const float4*)(offb + HW);
        float py[4] = {(float)h + oy.x, (float)h + oy.y,
                       (float)h + oy.z, (float)h + oy.w};
        float px[4] = {(float)(w + 0) + ox.x, (float)(w + 1) + ox.y,
                       (float)(w + 2) + ox.z, (float)(w + 3) + ox.w};
        float bd[4] = {INFINITY, INFINITY, INFINITY, INFINITY};
        int bi[4] = {0, 0, 0, 0};
#pragma unroll 8
        for (int k = 0; k < K; ++k) {
            float cy = cyb[k];
            float cx = cxb[k];
#pragma unroll
            for (int q = 0; q < 4; ++q) {
                float dy = py[q] - cy;
                float dx = px[q] - cx;
                float d = dy * dy + dx * dx;
                if (d < bd[q]) { bd[q] = d; bi[q] = k; }
            }
        }
        uchar4 s4 = *(const uchar4*)(semMap + base);
        int sa[4] = {s4.x, s4.y, s4.z, s4.w};
        float pout[4];
#pragma unroll
        for (int q = 0; q < 4; ++q) {
            int sem = sa[q];
            int pan;
            if (sem >= 1 && sem <= 7) {
                pan = anyV ? (clsL[bi[q]] * LABEL_DIVISOR + bi[q] + 1) : 0;
            } else {
                pan = (cntL[sem] >= STUFF_AREA) ? sem * LABEL_DIVISOR : 0;
            }
            pout[q] = (float)pan;
        }
        *(float4*)(out + O_PAN2 + base) = make_float4(pout[0], pout[1], pout[2], pout[3]);
    } else {
        // ---- fused geom3d + pan3d: 4 voxels/thread ----
        int bid3 = blockIdx.x - PAN2_BLOCKS;
        int b = bid3 / (F3D_BLOCKS / B);                 // uniform
        int base = bid3 * 1024 + t * 4;                  // index into [B*G3)
        int v = base - b * G3;
        if (t < K) clsL[t] = clA[b * K + t];
        if (t < C) lcnt[t] = 0;
        __syncthreads();
        // phase A: truncation + 3D argmax + fg counts
        float4 g = *(const float4*)(geom + base);
        float4 o = *(const float4*)(occ + base);
        float go[4];
        go[0] = (o.x <= 0.0f) ? TRUNCATION : g.x;
        go[1] = (o.y <= 0.0f) ? TRUNCATION : g.y;
        go[2] = (o.z <= 0.0f) ? TRUNCATION : g.z;
        go[3] = (o.w <= 0.0f) ? TRUNCATION : g.w;
        *(float4*)(out + O_GEOM + base) = make_float4(go[0], go[1], go[2], go[3]);
        const float* s = sem3in + (size_t)b * C * G3 + v;
        float4 s0 = *(const float4*)s;
        float bv[4] = {s0.x, s0.y, s0.z, s0.w};
        int bc[4] = {0, 0, 0, 0};
#pragma unroll
        for (int c = 1; c < C; ++c) {
            float4 x = *(const float4*)(s + (size_t)c * G3);
            float xa[4] = {x.x, x.y, x.z, x.w};
#pragma unroll
            for (int q = 0; q < 4; ++q)
                if (xa[q] > bv[q]) { bv[q] = xa[q]; bc[q] = c; }
        }
        *(uchar4*)(sem3Map + base) =
            make_uchar4((uint8_t)bc[0], (uint8_t)bc[1], (uint8_t)bc[2], (uint8_t)bc[3]);
        bool fg[4];
#pragma unroll
        for (int q = 0; q < 4; ++q) {
            fg[q] = fabsf(go[q]) < TSDF_THRESH;
            if (fg[q]) atomicAdd(&lcnt[bc[q]], 1);
        }
        __syncthreads();
        if (t < C) atomicAdd(&counts3d[b * C + t], lcnt[t]);
        // phase B: projection + 128-center argmin (exact FP order)
        float fx = intr[(size_t)b * 9 + 0];              // uniform
        float fy = intr[(size_t)b * 9 + 4];
        float u0 = intr[(size_t)b * 9 + 2];
        float v0 = intr[(size_t)b * 9 + 5];
        int i = v / (G * G);
        int rem = v - i * (G * G);
        int j = rem / G;
        int k0 = rem - j * G;                            // k0..k0+3 same row
        const float* ob = off3 + (size_t)b * 3 * G3 + v;
        float4 o0 = *(const float4*)ob;
        float4 o1 = *(const float4*)(ob + G3);
        float4 o2 = *(const float4*)(ob + 2 * (size_t)G3);
        float oa0[4] = {o0.x, o0.y, o0.z, o0.w};
        float oa1[4] = {o1.x, o1.y, o1.z, o1.w};
        float oa2[4] = {o2.x, o2.y, o2.z, o2.w};
        float uu[4], vv[4];
#pragma unroll
        for (int q = 0; q < 4; ++q) {
            float Xm = ((float)i + oa0[q] + 0.5f) * VOXEL_SIZE - HALF_EXT;
            float Ym = ((float)j + oa1[q] + 0.5f) * VOXEL_SIZE - HALF_EXT;
            float Zr = 0.0f + ((float)(k0 + q) + oa2[q] + 0.5f) * VOXEL_SIZE;
            float Zm = fminf(fmaxf(Zr, 0.1f), DEPTH_MAX);
            uu[q] = fx * Xm / Zm + u0;
            vv[q] = fy * Ym / Zm + v0;
        }
        bool anyV = scA[b * K] > CENTER_THRESHOLD;       // uniform
        const float* cyb = cyV + b * K;
        const float* cxb = cxV + b * K;
        float bd[4] = {INFINITY, INFINITY, INFINITY, INFINITY};
        int bi[4] = {0, 0, 0, 0};
#pragma unroll 8
        for (int k = 0; k < K; ++k) {
            float cy = cyb[k];
            float cx = cxb[k];
#pragma unroll
            for (int q = 0; q < 4; ++q) {
                float dv = vv[q] - cy;
                float du = uu[q] - cx;
                float d = dv * dv + du * du;
                if (d < bd[q]) { bd[q] = d; bi[q] = k; }
            }
        }
        float pout[4];
#pragma unroll
        for (int q = 0; q < 4; ++q) {
            int sem = bc[q];
            int pan = 0;
            if (sem >= 1 && sem <= 7) {        // thing: final value now
                pan = anyV ? (clsL[bi[q]] * LABEL_DIVISOR + bi[q] + 1) : 0;
                if (!fg[q]) pan = 0;
            }                                  // stuff: 0 here, k_stuff fills
            pout[q] = (float)pan;
        }
        *(float4*)(out + O_PAN3 + base) = make_float4(pout[0], pout[1], pout[2], pout[3]);
    }
}

// Fill stuff voxels (needs completed counts3d). Sparse predicated stores.
__global__ void k_stuff(const uint8_t* __restrict__ sem3Map,
                        const int* __restrict__ counts3d,
                        const float* __restrict__ geomOut,
                        float* __restrict__ out) {
    __shared__ int cntL[C];
    int t = threadIdx.x;
    int b = blockIdx.x / (F3D_BLOCKS / B);               // uniform
    if (t < C) cntL[t] = counts3d[b * C + t];
    __syncthreads();
    int base = blockIdx.x * 1024 + t * 4;
    uchar4 s4 = *(const uchar4*)(sem3Map + base);
    float4 g4 = *(const float4*)(geomOut + base);
    int sa[4] = {s4.x, s4.y, s4.z, s4.w};
    float ga[4] = {g4.x, g4.y, g4.z, g4.w};
#pragma unroll
    for (int q = 0; q < 4; ++q) {
        int sem = sa[q];
        bool stuff = !(sem >= 1 && sem <= 7);
        if (stuff && sem != 0 && fabsf(ga[q]) < TSDF_THRESH &&
            cntL[sem] >= STUFF_AREA) {
            out[O_PAN3 + base + q] = (float)(sem * LABEL_DIVISOR);
        }
    }
}

extern "C" void kernel_launch(void* const* d_in, const int* in_sizes, int n_in,
                              void* d_out, int out_size, void* d_ws, size_t ws_size,
                              hipStream_t stream) {
    const float* semantic2d  = (const float*)d_in[0];
    const float* center2d    = (const float*)d_in[1];
    const float* offset2d    = (const float*)d_in[2];
    const float* geometry    = (const float*)d_in[3];
    const float* occupancy3d = (const float*)d_in[4];
    const float* semantic3d  = (const float*)d_in[5];
    const float* offset3d    = (const float*)d_in[6];
    const float* intrinsic   = (const float*)d_in[7];
    float* out = (float*)d_out;
    char* ws = (char*)d_ws;

    int* candCount = (int*)(ws + 0);      // [B]
    int* counts2d  = (int*)(ws + 16);     // [B*C]
    int* counts3d  = (int*)(ws + 112);    // [B*C]
    float* cyA = (float*)(ws + WS_CY);
    float* cxA = (float*)(ws + WS_CX);
    float* scA = (float*)(ws + WS_SC);
    int*   clA = (int*)(ws + WS_CL);
    uint8_t* semMap  = (uint8_t*)(ws + WS_SEM2);
    uint8_t* nmsMask = (uint8_t*)(ws + WS_NMS);
    float* candVal = (float*)(ws + WS_CV);
    int*   candIdx = (int*)(ws + WS_CI);
    uint8_t* sem3Map = (uint8_t*)(ws + WS_SEM3);
    float* cyV = (float*)(ws + WS_CYV);
    float* cxV = (float*)(ws + WS_CXV);

    hipMemsetAsync(d_ws, 0, 256, stream);

    k_pre2d<<<B * H, 256, 0, stream>>>(semantic2d, center2d, semMap, nmsMask,
                                       candVal, candIdx, candCount, counts2d);
    k_topk<<<B * TOPK_NB, 256, 0, stream>>>(semMap, nmsMask, candVal, candIdx, candCount,
                                            cyA, cxA, scA, clA, cyV, cxV, out);
    k_fuse<<<PAN2_BLOCKS + F3D_BLOCKS, 256, 0, stream>>>(
        geometry, occupancy3d, semantic3d, sem3Map, counts3d,
        offset2d, semMap, counts2d, offset3d, intrinsic,
        scA, clA, cyV, cxV, out);
    k_stuff<<<F3D_BLOCKS, 256, 0, stream>>>(sem3Map, counts3d, out + O_GEOM, out);
}

// Round 6
// 104.055 us; speedup vs baseline: 1.3208x; 1.0394x over previous
//
#include <hip/hip_runtime.h>
#include <stdint.h>

constexpr int B = 2, H = 256, W = 256, G = 96, C = 12, K = 128;
constexpr int HW = H * W;          // 65536
constexpr int G3 = G * G * G;      // 884736
constexpr float CENTER_THRESHOLD = 0.1f;
constexpr int STUFF_AREA = 2048;
constexpr int LABEL_DIVISOR = 1000;
constexpr float VOXEL_SIZE = 0.0625f;
constexpr float TRUNCATION = 3.0f;
constexpr float TSDF_THRESH = 1.5f;
constexpr float DEPTH_MAX = 6.0f;
constexpr float HALF_EXT = 3.0f;   // G*VOXEL_SIZE/2
constexpr int TOPK_CAP = 6144;     // LDS candidate capacity (48 KB)
constexpr int TOPK_NB = 64;        // blocks per batch for k_topk
constexpr int PAN2_BLOCKS = (B * HW) / 1024;   // 128
constexpr int F3D_BLOCKS = (B * G3) / 1024;    // 1728

// output layout (floats)
constexpr size_t O_PAN2 = 0;
constexpr size_t O_PAN3 = 131072;
constexpr size_t O_GEOM = 1900544;
constexpr size_t O_CENT = 3670016;
constexpr size_t O_CLS  = 3670528;
constexpr size_t O_SCR  = 3670784;

// ws layout (bytes)
constexpr size_t WS_SC   = 2304;
constexpr size_t WS_CL   = 3328;
constexpr size_t WS_SEM2 = 4352;
constexpr size_t WS_NMS  = 135424;
constexpr size_t WS_CV   = 266496;
constexpr size_t WS_CI   = 790784;
constexpr size_t WS_STUF = 1315072;   // B*G3 bytes (stuff candidate map)
constexpr size_t WS_CYV  = 3084544;
constexpr size_t WS_CXV  = 3085568;

// 2 rows per block, 2 pixels per thread. Separable clamped 7x7 max.
__global__ __launch_bounds__(256)
void k_pre2d(const float* __restrict__ sem2in,
             const float* __restrict__ center2d,
             uint8_t* __restrict__ semMap, uint8_t* __restrict__ nmsMask,
             float* __restrict__ candVal, int* __restrict__ candIdx,
             int* __restrict__ candCount, int* __restrict__ counts2d) {
    __shared__ float vm[2][W];
    __shared__ int lcnt[C];
    int t = threadIdx.x;
    int r = t >> 7;                    // row within block (wave-uniform)
    int c0 = (t & 127) * 2;
    int b = blockIdx.x / (H / 2);
    int h = (blockIdx.x % (H / 2)) * 2 + r;
    if (t < C) lcnt[t] = 0;
    const float* hmb = center2d + (size_t)b * HW;
    int h0 = max(h - 3, 0), h1 = min(h + 3, H - 1);
    float2 hm2 = *(const float2*)(hmb + h * W + c0);
    float m0 = -INFINITY, m1 = -INFINITY;
    for (int y = h0; y <= h1; ++y) {
        float2 v = *(const float2*)(hmb + y * W + c0);
        m0 = fmaxf(m0, v.x);
        m1 = fmaxf(m1, v.y);
    }
    vm[r][c0] = m0;
    vm[r][c0 + 1] = m1;
    __syncthreads();
    float mm[2];
#pragma unroll
    for (int q = 0; q < 2; ++q) {
        int c = c0 + q;
        int w0 = max(c - 3, 0), w1 = min(c + 3, W - 1);
        float mx = -INFINITY;
        for (int x = w0; x <= w1; ++x) mx = fmaxf(mx, vm[r][x]);
        mm[q] = mx;
    }
    // semantic argmax (first max wins)
    const float* s = sem2in + (size_t)b * C * HW + h * W + c0;
    float2 s0 = *(const float2*)s;
    float bv[2] = {s0.x, s0.y};
    int cls[2] = {0, 0};
#pragma unroll
    for (int c = 1; c < C; ++c) {
        float2 x = *(const float2*)(s + (size_t)c * HW);
        if (x.x > bv[0]) { bv[0] = x.x; cls[0] = c; }
        if (x.y > bv[1]) { bv[1] = x.y; cls[1] = c; }
    }
    int p = h * W + c0;
    int gid = b * HW + p;
    semMap[gid] = (uint8_t)cls[0];
    semMap[gid + 1] = (uint8_t)cls[1];
    atomicAdd(&lcnt[cls[0]], 1);
    atomicAdd(&lcnt[cls[1]], 1);
    float hma[2] = {hm2.x, hm2.y};
#pragma unroll
    for (int q = 0; q < 2; ++q) {
        bool cand = (hma[q] == mm[q]);
        nmsMask[gid + q] = cand ? 1 : 0;
        if (cand) {
            int pos = atomicAdd(&candCount[b], 1);
            if (pos < HW) {
                candVal[(size_t)b * HW + pos] = hma[q];
                candIdx[(size_t)b * HW + pos] = p + q;
            }
        }
    }
    __syncthreads();
    if (t < C) atomicAdd(&counts2d[b * C + t], lcnt[t]);
}

// Wave-per-candidate exact top-k (rank scatter; order-invariant).
// Emits cyV/cxV = valid ? center : +INF, scA, clA, and the out[] entries.
__global__ __launch_bounds__(256)
void k_topk(const uint8_t* __restrict__ semMap, const uint8_t* __restrict__ nmsMask,
            const float* __restrict__ candVal, const int* __restrict__ candIdx,
            const int* __restrict__ candCount,
            float* __restrict__ scA, int* __restrict__ clA,
            float* __restrict__ cyV, float* __restrict__ cxV,
            float* __restrict__ out) {
    __shared__ float2 cd[TOPK_CAP];
    int b = blockIdx.x / TOPK_NB;
    int sub = blockIdx.x % TOPK_NB;
    int t = threadIdx.x;
    int lane = t & 63;
    int wv = sub * 4 + (t >> 6);
    int n = candCount[b];
    if (n > HW) n = HW;
    const float* cv = candVal + (size_t)b * HW;
    const int*  ci = candIdx + (size_t)b * HW;
    bool useLds = (n <= TOPK_CAP);
    if (useLds) {
        for (int i = t; i < n; i += 256)
            cd[i] = make_float2(cv[i], __int_as_float(ci[i]));
    }
    __syncthreads();
    for (int i = wv; i < n; i += TOPK_NB * 4) {
        float v; int id;
        if (useLds) { float2 c = cd[i]; v = c.x; id = __float_as_int(c.y); }
        else        { v = cv[i]; id = ci[i]; }
        int r = 0;
        if (useLds) {
            for (int j = lane; j < n; j += 64) {
                float2 c = cd[j];
                r += (c.x > v) || (c.x == v && __float_as_int(c.y) < id);
            }
        } else {
            for (int j = lane; j < n; j += 64) {
                float vj = cv[j]; int ij = ci[j];
                r += (vj > v) || (vj == v && ij < id);
            }
        }
#pragma unroll
        for (int off = 32; off >= 1; off >>= 1) r += __shfl_xor(r, off, 64);
        if (lane == 0 && r < K) {
            int o = b * K + r;
            float fy = (float)(id / W);
            float fx = (float)(id % W);
            int cls = (int)semMap[(size_t)b * HW + id];
            bool val = v > CENTER_THRESHOLD;
            scA[o] = v; clA[o] = cls;
            cyV[o] = val ? fy : INFINITY;
            cxV[o] = val ? fx : INFINITY;
            out[O_CENT + (size_t)o * 2 + 0] = fy;
            out[O_CENT + (size_t)o * 2 + 1] = fx;
            out[O_CLS + o] = (float)cls;
            out[O_SCR + o] = v;
        }
    }
    if (sub == 0 && t == 0 && n < K) {
        int r = n;
        for (int p = 0; p < HW && r < K; ++p) {
            if (!nmsMask[(size_t)b * HW + p]) {
                int o = b * K + r;
                float fy = (float)(p / W);
                float fx = (float)(p % W);
                int cls = (int)semMap[(size_t)b * HW + p];
                scA[o] = 0.0f; clA[o] = cls;
                cyV[o] = INFINITY;
                cxV[o] = INFINITY;
                out[O_CENT + (size_t)o * 2 + 0] = fy;
                out[O_CENT + (size_t)o * 2 + 1] = fx;
                out[O_CLS + o] = (float)cls;
                out[O_SCR + o] = 0.0f;
                ++r;
            }
        }
    }
}

// Fused: pan2d blocks [0,PAN2_BLOCKS) + {geom3d+pan3d} blocks (rest).
// Centers staged in LDS; counts3d flush deferred to kernel end so the
// argmin VALU loop starts as soon as a wave's own loads return.
__global__ __launch_bounds__(256)
void k_fuse(const float* __restrict__ geom, const float* __restrict__ occ,
            const float* __restrict__ sem3in,
            uint8_t* __restrict__ stuffCand, int* __restrict__ counts3d,
            const float* __restrict__ offset2d,
            const uint8_t* __restrict__ semMap,
            const int* __restrict__ counts2d,
            const float* __restrict__ off3,
            const float* __restrict__ intr,
            const float* __restrict__ scA, const int* __restrict__ clA,
            const float* __restrict__ cyV, const float* __restrict__ cxV,
            float* __restrict__ out) {
#pragma clang fp contract(off)
    __shared__ float2 cc[K];
    __shared__ int clsL[K];
    __shared__ int lcnt[C];
    __shared__ int cntL[C];
    int t = threadIdx.x;
    if (blockIdx.x < PAN2_BLOCKS) {
        // ---- pan2d: 4 pixels/thread ----
        int b = blockIdx.x / (PAN2_BLOCKS / B);          // uniform
        int base = blockIdx.x * 1024 + t * 4;
        int p = base - b * HW;
        if (t < K) {
            cc[t] = make_float2(cyV[b * K + t], cxV[b * K + t]);
            clsL[t] = clA[b * K + t];
        }
        if (t < C) cntL[t] = counts2d[b * C + t];
        __syncthreads();
        bool anyV = scA[b * K] > CENTER_THRESHOLD;       // uniform
        int h = p / W, w = p % W;
        const float* offb = offset2d + (size_t)b * 2 * HW + p;
        float4 oy = *(const float4*)offb;
        float4 ox = *(const float4*)(offb + HW);
        float py[4] = {(float)h + oy.x, (float)h + oy.y,
                       (float)h + oy.z, (float)h + oy.w};
        float px[4] = {(float)(w + 0) + ox.x, (float)(w + 1) + ox.y,
                       (float)(w + 2) + ox.z, (float)(w + 3) + ox.w};
        float bd[4] = {INFINITY, INFINITY, INFINITY, INFINITY};
        int bi[4] = {0, 0, 0, 0};
#pragma unroll 8
        for (int k = 0; k < K; ++k) {
            float2 c = cc[k];
#pragma unroll
            for (int q = 0; q < 4; ++q) {
                float dy = py[q] - c.x;
                float dx = px[q] - c.y;
                float d = dy * dy + dx * dx;
                if (d < bd[q]) { bd[q] = d; bi[q] = k; }
            }
        }
        uchar4 s4 = *(const uchar4*)(semMap + base);
        int sa[4] = {s4.x, s4.y, s4.z, s4.w};
        float pout[4];
#pragma unroll
        for (int q = 0; q < 4; ++q) {
            int sem = sa[q];
            int pan;
            if (sem >= 1 && sem <= 7) {
                pan = anyV ? (clsL[bi[q]] * LABEL_DIVISOR + bi[q] + 1) : 0;
            } else {
                pan = (cntL[sem] >= STUFF_AREA) ? sem * LABEL_DIVISOR : 0;
            }
            pout[q] = (float)pan;
        }
        *(float4*)(out + O_PAN2 + base) = make_float4(pout[0], pout[1], pout[2], pout[3]);
    } else {
        // ---- fused geom3d + pan3d: 4 voxels/thread ----
        int bid3 = blockIdx.x - PAN2_BLOCKS;
        int b = bid3 / (F3D_BLOCKS / B);                 // uniform
        int base = bid3 * 1024 + t * 4;                  // index into [B*G3)
        int v = base - b * G3;
        if (t < K) {
            cc[t] = make_float2(cyV[b * K + t], cxV[b * K + t]);
            clsL[t] = clA[b * K + t];
        }
        if (t < C) lcnt[t] = 0;
        __syncthreads();
        // phase A: truncation + 3D argmax + fg counts (LDS only, no barrier)
        float4 g = *(const float4*)(geom + base);
        float4 o = *(const float4*)(occ + base);
        float go[4];
        go[0] = (o.x <= 0.0f) ? TRUNCATION : g.x;
        go[1] = (o.y <= 0.0f) ? TRUNCATION : g.y;
        go[2] = (o.z <= 0.0f) ? TRUNCATION : g.z;
        go[3] = (o.w <= 0.0f) ? TRUNCATION : g.w;
        *(float4*)(out + O_GEOM + base) = make_float4(go[0], go[1], go[2], go[3]);
        const float* s = sem3in + (size_t)b * C * G3 + v;
        float4 s0 = *(const float4*)s;
        float bv[4] = {s0.x, s0.y, s0.z, s0.w};
        int bc[4] = {0, 0, 0, 0};
#pragma unroll
        for (int c = 1; c < C; ++c) {
            float4 x = *(const float4*)(s + (size_t)c * G3);
            float xa[4] = {x.x, x.y, x.z, x.w};
#pragma unroll
            for (int q = 0; q < 4; ++q)
                if (xa[q] > bv[q]) { bv[q] = xa[q]; bc[q] = c; }
        }
        bool fg[4];
        uint8_t sc4[4];
#pragma unroll
        for (int q = 0; q < 4; ++q) {
            fg[q] = fabsf(go[q]) < TSDF_THRESH;
            if (fg[q]) atomicAdd(&lcnt[bc[q]], 1);
            sc4[q] = (fg[q] && bc[q] >= 8) ? (uint8_t)bc[q] : 0;
        }
        *(uchar4*)(stuffCand + base) = make_uchar4(sc4[0], sc4[1], sc4[2], sc4[3]);
        // phase B: projection + 128-center argmin (exact FP order)
        float fx = intr[(size_t)b * 9 + 0];              // uniform
        float fy = intr[(size_t)b * 9 + 4];
        float u0 = intr[(size_t)b * 9 + 2];
        float v0 = intr[(size_t)b * 9 + 5];
        int i = v / (G * G);
        int rem = v - i * (G * G);
        int j = rem / G;
        int k0 = rem - j * G;                            // k0..k0+3 same row
        const float* ob = off3 + (size_t)b * 3 * G3 + v;
        float4 o0 = *(const float4*)ob;
        float4 o1 = *(const float4*)(ob + G3);
        float4 o2 = *(const float4*)(ob + 2 * (size_t)G3);
        float oa0[4] = {o0.x, o0.y, o0.z, o0.w};
        float oa1[4] = {o1.x, o1.y, o1.z, o1.w};
        float oa2[4] = {o2.x, o2.y, o2.z, o2.w};
        float uu[4], vv[4];
#pragma unroll
        for (int q = 0; q < 4; ++q) {
            float Xm = ((float)i + oa0[q] + 0.5f) * VOXEL_SIZE - HALF_EXT;
            float Ym = ((float)j + oa1[q] + 0.5f) * VOXEL_SIZE - HALF_EXT;
            float Zr = 0.0f + ((float)(k0 + q) + oa2[q] + 0.5f) * VOXEL_SIZE;
            float Zm = fminf(fmaxf(Zr, 0.1f), DEPTH_MAX);
            uu[q] = fx * Xm / Zm + u0;
            vv[q] = fy * Ym / Zm + v0;
        }
        bool anyV = scA[b * K] > CENTER_THRESHOLD;       // uniform
        float bd[4] = {INFINITY, INFINITY, INFINITY, INFINITY};
        int bi[4] = {0, 0, 0, 0};
#pragma unroll 8
        for (int k = 0; k < K; ++k) {
            float2 c = cc[k];
#pragma unroll
            for (int q = 0; q < 4; ++q) {
                float dv = vv[q] - c.x;
                float du = uu[q] - c.y;
                float d = dv * dv + du * du;
                if (d < bd[q]) { bd[q] = d; bi[q] = k; }
            }
        }
        float pout[4];
#pragma unroll
        for (int q = 0; q < 4; ++q) {
            int sem = bc[q];
            int pan = 0;
            if (sem >= 1 && sem <= 7) {        // thing: final value now
                pan = anyV ? (clsL[bi[q]] * LABEL_DIVISOR + bi[q] + 1) : 0;
                if (!fg[q]) pan = 0;
            }                                  // stuff: 0 here, k_stuff fills
            pout[q] = (float)pan;
        }
        *(float4*)(out + O_PAN3 + base) = make_float4(pout[0], pout[1], pout[2], pout[3]);
        __syncthreads();
        if (t < C) atomicAdd(&counts3d[b * C + t], lcnt[t]);
    }
}

// Fill stuff voxels (needs completed counts3d). 16 voxels/thread, 1.7 MB read.
__global__ __launch_bounds__(256)
void k_stuff(const uint8_t* __restrict__ stuffCand,
             const int* __restrict__ counts3d,
             float* __restrict__ out) {
    __shared__ int cntL[C];
    constexpr int BPB = F3D_BLOCKS / 4 / B;              // 216 blocks per batch
    int t = threadIdx.x;
    int b = blockIdx.x / BPB;                            // uniform
    if (t < C) cntL[t] = counts3d[b * C + t];
    __syncthreads();
    int base = blockIdx.x * 4096 + t * 16;
    uint4 packed = *(const uint4*)(stuffCand + base);
    uint32_t wds[4] = {packed.x, packed.y, packed.z, packed.w};
#pragma unroll
    for (int wq = 0; wq < 4; ++wq) {
        uint32_t wd = wds[wq];
#pragma unroll
        for (int bq = 0; bq < 4; ++bq) {
            int c = (wd >> (8 * bq)) & 0xFF;
            if (c != 0 && cntL[c] >= STUFF_AREA) {
                out[O_PAN3 + base + wq * 4 + bq] = (float)(c * LABEL_DIVISOR);
            }
        }
    }
}

extern "C" void kernel_launch(void* const* d_in, const int* in_sizes, int n_in,
                              void* d_out, int out_size, void* d_ws, size_t ws_size,
                              hipStream_t stream) {
    const float* semantic2d  = (const float*)d_in[0];
    const float* center2d    = (const float*)d_in[1];
    const float* offset2d    = (const float*)d_in[2];
    const float* geometry    = (const float*)d_in[3];
    const float* occupancy3d = (const float*)d_in[4];
    const float* semantic3d  = (const float*)d_in[5];
    const float* offset3d    = (const float*)d_in[6];
    const float* intrinsic   = (const float*)d_in[7];
    float* out = (float*)d_out;
    char* ws = (char*)d_ws;

    int* candCount = (int*)(ws + 0);      // [B]
    int* counts2d  = (int*)(ws + 16);     // [B*C]
    int* counts3d  = (int*)(ws + 112);    // [B*C]
    float* scA = (float*)(ws + WS_SC);
    int*   clA = (int*)(ws + WS_CL);
    uint8_t* semMap  = (uint8_t*)(ws + WS_SEM2);
    uint8_t* nmsMask = (uint8_t*)(ws + WS_NMS);
    float* candVal = (float*)(ws + WS_CV);
    int*   candIdx = (int*)(ws + WS_CI);
    uint8_t* stuffCand = (uint8_t*)(ws + WS_STUF);
    float* cyV = (float*)(ws + WS_CYV);
    float* cxV = (float*)(ws + WS_CXV);

    hipMemsetAsync(d_ws, 0, 256, stream);

    k_pre2d<<<B * (H / 2), 256, 0, stream>>>(semantic2d, center2d, semMap, nmsMask,
                                             candVal, candIdx, candCount, counts2d);
    k_topk<<<B * TOPK_NB, 256, 0, stream>>>(semMap, nmsMask, candVal, candIdx, candCount,
                                            scA, clA, cyV, cxV, out);
    k_fuse<<<PAN2_BLOCKS + F3D_BLOCKS, 256, 0, stream>>>(
        geometry, occupancy3d, semantic3d, stuffCand, counts3d,
        offset2d, semMap, counts2d, offset3d, intrinsic,
        scA, clA, cyV, cxV, out);
    k_stuff<<<F3D_BLOCKS / 4, 256, 0, stream>>>(stuffCand, counts3d, out);
}

// Round 7
// 93.656 us; speedup vs baseline: 1.4674x; 1.1110x over previous
//
#include <hip/hip_runtime.h>
#include <stdint.h>

constexpr int B = 2, H = 256, W = 256, G = 96, C = 12, K = 128;
constexpr int HW = H * W;          // 65536
constexpr int G3 = G * G * G;      // 884736
constexpr float CENTER_THRESHOLD = 0.1f;
constexpr int STUFF_AREA = 2048;
constexpr int LABEL_DIVISOR = 1000;
constexpr float VOXEL_SIZE = 0.0625f;
constexpr float TRUNCATION = 3.0f;
constexpr float TSDF_THRESH = 1.5f;
constexpr float DEPTH_MAX = 6.0f;
constexpr float HALF_EXT = 3.0f;   // G*VOXEL_SIZE/2
constexpr int TOPK_CAP = 6144;     // LDS candidate capacity (48 KB)
constexpr int TOPK_NB = 64;        // blocks per batch for k_topk
constexpr int PAN2_BLOCKS = (B * HW) / 1024;   // 128
constexpr int F3D_BLOCKS = (B * G3) / 1024;    // 1728

// output layout (floats)
constexpr size_t O_PAN2 = 0;
constexpr size_t O_PAN3 = 131072;
constexpr size_t O_GEOM = 1900544;
constexpr size_t O_CENT = 3670016;
constexpr size_t O_CLS  = 3670528;
constexpr size_t O_SCR  = 3670784;

// ws layout (bytes)
constexpr size_t WS_SC   = 2304;
constexpr size_t WS_CL   = 3328;
constexpr size_t WS_SEM2 = 4352;
constexpr size_t WS_NMS  = 135424;
constexpr size_t WS_CV   = 266496;
constexpr size_t WS_CI   = 790784;
constexpr size_t WS_STUF = 1315072;   // B*G3 bytes (stuff candidate map)
constexpr size_t WS_CYV  = 3084544;
constexpr size_t WS_CXV  = 3085568;

typedef float f32x2 __attribute__((ext_vector_type(2)));

// VOP3P packed fp32: elementwise IEEE-identical to scalar v_add/v_mul.
__device__ inline f32x2 pk_add(f32x2 a, f32x2 b) {
    f32x2 d;
    asm("v_pk_add_f32 %0, %1, %2" : "=v"(d) : "v"(a), "v"(b));
    return d;
}
__device__ inline f32x2 pk_mul(f32x2 a, f32x2 b) {
    f32x2 d;
    asm("v_pk_mul_f32 %0, %1, %2" : "=v"(d) : "v"(a), "v"(b));
    return d;
}

// 2 rows per block, 2 pixels per thread. Separable clamped 7x7 max.
__global__ __launch_bounds__(256)
void k_pre2d(const float* __restrict__ sem2in,
             const float* __restrict__ center2d,
             uint8_t* __restrict__ semMap, uint8_t* __restrict__ nmsMask,
             float* __restrict__ candVal, int* __restrict__ candIdx,
             int* __restrict__ candCount, int* __restrict__ counts2d) {
    __shared__ float vm[2][W];
    __shared__ int lcnt[C];
    int t = threadIdx.x;
    int r = t >> 7;                    // row within block (wave-uniform)
    int c0 = (t & 127) * 2;
    int b = blockIdx.x / (H / 2);
    int h = (blockIdx.x % (H / 2)) * 2 + r;
    if (t < C) lcnt[t] = 0;
    const float* hmb = center2d + (size_t)b * HW;
    int h0 = max(h - 3, 0), h1 = min(h + 3, H - 1);
    float2 hm2 = *(const float2*)(hmb + h * W + c0);
    float m0 = -INFINITY, m1 = -INFINITY;
    for (int y = h0; y <= h1; ++y) {
        float2 v = *(const float2*)(hmb + y * W + c0);
        m0 = fmaxf(m0, v.x);
        m1 = fmaxf(m1, v.y);
    }
    vm[r][c0] = m0;
    vm[r][c0 + 1] = m1;
    __syncthreads();
    float mm[2];
#pragma unroll
    for (int q = 0; q < 2; ++q) {
        int c = c0 + q;
        int w0 = max(c - 3, 0), w1 = min(c + 3, W - 1);
        float mx = -INFINITY;
        for (int x = w0; x <= w1; ++x) mx = fmaxf(mx, vm[r][x]);
        mm[q] = mx;
    }
    // semantic argmax (first max wins)
    const float* s = sem2in + (size_t)b * C * HW + h * W + c0;
    float2 s0 = *(const float2*)s;
    float bv[2] = {s0.x, s0.y};
    int cls[2] = {0, 0};
#pragma unroll
    for (int c = 1; c < C; ++c) {
        float2 x = *(const float2*)(s + (size_t)c * HW);
        if (x.x > bv[0]) { bv[0] = x.x; cls[0] = c; }
        if (x.y > bv[1]) { bv[1] = x.y; cls[1] = c; }
    }
    int p = h * W + c0;
    int gid = b * HW + p;
    semMap[gid] = (uint8_t)cls[0];
    semMap[gid + 1] = (uint8_t)cls[1];
    atomicAdd(&lcnt[cls[0]], 1);
    atomicAdd(&lcnt[cls[1]], 1);
    float hma[2] = {hm2.x, hm2.y};
#pragma unroll
    for (int q = 0; q < 2; ++q) {
        bool cand = (hma[q] == mm[q]);
        nmsMask[gid + q] = cand ? 1 : 0;
        if (cand) {
            int pos = atomicAdd(&candCount[b], 1);
            if (pos < HW) {
                candVal[(size_t)b * HW + pos] = hma[q];
                candIdx[(size_t)b * HW + pos] = p + q;
            }
        }
    }
    __syncthreads();
    if (t < C) atomicAdd(&counts2d[b * C + t], lcnt[t]);
}

// Wave-per-candidate exact top-k (rank scatter; order-invariant).
__global__ __launch_bounds__(256)
void k_topk(const uint8_t* __restrict__ semMap, const uint8_t* __restrict__ nmsMask,
            const float* __restrict__ candVal, const int* __restrict__ candIdx,
            const int* __restrict__ candCount,
            float* __restrict__ scA, int* __restrict__ clA,
            float* __restrict__ cyV, float* __restrict__ cxV,
            float* __restrict__ out) {
    __shared__ float2 cd[TOPK_CAP];
    int b = blockIdx.x / TOPK_NB;
    int sub = blockIdx.x % TOPK_NB;
    int t = threadIdx.x;
    int lane = t & 63;
    int wv = sub * 4 + (t >> 6);
    int n = candCount[b];
    if (n > HW) n = HW;
    const float* cv = candVal + (size_t)b * HW;
    const int*  ci = candIdx + (size_t)b * HW;
    bool useLds = (n <= TOPK_CAP);
    if (useLds) {
        for (int i = t; i < n; i += 256)
            cd[i] = make_float2(cv[i], __int_as_float(ci[i]));
    }
    __syncthreads();
    for (int i = wv; i < n; i += TOPK_NB * 4) {
        float v; int id;
        if (useLds) { float2 c = cd[i]; v = c.x; id = __float_as_int(c.y); }
        else        { v = cv[i]; id = ci[i]; }
        int r = 0;
        if (useLds) {
            for (int j = lane; j < n; j += 64) {
                float2 c = cd[j];
                r += (c.x > v) || (c.x == v && __float_as_int(c.y) < id);
            }
        } else {
            for (int j = lane; j < n; j += 64) {
                float vj = cv[j]; int ij = ci[j];
                r += (vj > v) || (vj == v && ij < id);
            }
        }
#pragma unroll
        for (int off = 32; off >= 1; off >>= 1) r += __shfl_xor(r, off, 64);
        if (lane == 0 && r < K) {
            int o = b * K + r;
            float fy = (float)(id / W);
            float fx = (float)(id % W);
            int cls = (int)semMap[(size_t)b * HW + id];
            bool val = v > CENTER_THRESHOLD;
            scA[o] = v; clA[o] = cls;
            cyV[o] = val ? fy : INFINITY;
            cxV[o] = val ? fx : INFINITY;
            out[O_CENT + (size_t)o * 2 + 0] = fy;
            out[O_CENT + (size_t)o * 2 + 1] = fx;
            out[O_CLS + o] = (float)cls;
            out[O_SCR + o] = v;
        }
    }
    if (sub == 0 && t == 0 && n < K) {
        int r = n;
        for (int p = 0; p < HW && r < K; ++p) {
            if (!nmsMask[(size_t)b * HW + p]) {
                int o = b * K + r;
                float fy = (float)(p / W);
                float fx = (float)(p % W);
                int cls = (int)semMap[(size_t)b * HW + p];
                scA[o] = 0.0f; clA[o] = cls;
                cyV[o] = INFINITY;
                cxV[o] = INFINITY;
                out[O_CENT + (size_t)o * 2 + 0] = fy;
                out[O_CENT + (size_t)o * 2 + 1] = fx;
                out[O_CLS + o] = (float)cls;
                out[O_SCR + o] = 0.0f;
                ++r;
            }
        }
    }
}

// Exact group-min argmin over 128 centers for 4 points held as 2 f32x2 pairs.
// cc4 = (-cy,-cy,-cx,-cx) per center; cc2 = (-cy,-cx).
// Pass 1: per-group (8x16) min chains via pk ops (no index tracking).
// Merge: strict < keeps first group attaining the global min.
// Pass 2: rescan winning group's 16 centers, reverse scan -> first-k-wins.
// All FP ops bit-identical to the scalar reference tree.
__device__ inline void argmin128(const float4* __restrict__ cc4,
                                 const float2* __restrict__ cc2,
                                 const f32x2 vv2[2], const f32x2 uu2[2],
                                 int bi[4]) {
#pragma clang fp contract(off)
    f32x2 m0 = {INFINITY, INFINITY}, m1 = {INFINITY, INFINITY};
    int gs[4] = {0, 0, 0, 0};
    for (int g = 0; g < 8; ++g) {
        f32x2 b0 = {INFINITY, INFINITY}, b1 = {INFINITY, INFINITY};
#pragma unroll
        for (int kk = 0; kk < 16; ++kk) {
            float4 c4 = cc4[(g << 4) + kk];
            f32x2 ncy; ncy[0] = c4.x; ncy[1] = c4.y;
            f32x2 ncx; ncx[0] = c4.z; ncx[1] = c4.w;
            f32x2 dv = pk_add(vv2[0], ncy);
            f32x2 du = pk_add(uu2[0], ncx);
            f32x2 d0 = pk_add(pk_mul(dv, dv), pk_mul(du, du));
            dv = pk_add(vv2[1], ncy);
            du = pk_add(uu2[1], ncx);
            f32x2 d1 = pk_add(pk_mul(dv, dv), pk_mul(du, du));
            b0[0] = fminf(b0[0], d0[0]); b0[1] = fminf(b0[1], d0[1]);
            b1[0] = fminf(b1[0], d1[0]); b1[1] = fminf(b1[1], d1[1]);
        }
        if (b0[0] < m0[0]) { m0[0] = b0[0]; gs[0] = g; }
        if (b0[1] < m0[1]) { m0[1] = b0[1]; gs[1] = g; }
        if (b1[0] < m1[0]) { m1[0] = b1[0]; gs[2] = g; }
        if (b1[1] < m1[1]) { m1[1] = b1[1]; gs[3] = g; }
    }
    float vq[4] = {vv2[0][0], vv2[0][1], vv2[1][0], vv2[1][1]};
    float uq[4] = {uu2[0][0], uu2[0][1], uu2[1][0], uu2[1][1]};
    float mq[4] = {m0[0], m0[1], m1[0], m1[1]};
#pragma unroll
    for (int q = 0; q < 4; ++q) {
        int kb = 0;
        int gbase = gs[q] << 4;
#pragma unroll
        for (int kk = 15; kk >= 0; --kk) {
            float2 c2 = cc2[gbase + kk];
            float dv = vq[q] + c2.x;
            float du = uq[q] + c2.y;
            float d = dv * dv + du * du;
            if (d == mq[q]) kb = kk;        // last write = smallest kk
        }
        bi[q] = gbase + kb;
    }
}

// Fused: pan2d blocks [0,PAN2_BLOCKS) + {geom3d+pan3d} blocks (rest).
__global__ __launch_bounds__(256)
void k_fuse(const float* __restrict__ geom, const float* __restrict__ occ,
            const float* __restrict__ sem3in,
            uint8_t* __restrict__ stuffCand, int* __restrict__ counts3d,
            const float* __restrict__ offset2d,
            const uint8_t* __restrict__ semMap,
            const int* __restrict__ counts2d,
            const float* __restrict__ off3,
            const float* __restrict__ intr,
            const float* __restrict__ scA, const int* __restrict__ clA,
            const float* __restrict__ cyV, const float* __restrict__ cxV,
            float* __restrict__ out) {
#pragma clang fp contract(off)
    __shared__ float4 cc4[K];
    __shared__ float2 cc2[K];
    __shared__ int clsL[K];
    __shared__ int lcnt[C];
    __shared__ int cntL[C];
    int t = threadIdx.x;
    if (blockIdx.x < PAN2_BLOCKS) {
        // ---- pan2d: 4 pixels/thread ----
        int b = blockIdx.x / (PAN2_BLOCKS / B);          // uniform
        int base = blockIdx.x * 1024 + t * 4;
        int p = base - b * HW;
        if (t < K) {
            float cy = cyV[b * K + t], cx = cxV[b * K + t];
            cc4[t] = make_float4(-cy, -cy, -cx, -cx);
            cc2[t] = make_float2(-cy, -cx);
            clsL[t] = clA[b * K + t];
        }
        if (t < C) cntL[t] = counts2d[b * C + t];
        __syncthreads();
        bool anyV = scA[b * K] > CENTER_THRESHOLD;       // uniform
        int h = p / W, w = p % W;
        const float* offb = offset2d + (size_t)b * 2 * HW + p;
        float4 oy = *(const float4*)offb;
        float4 ox = *(const float4*)(offb + HW);
        f32x2 py2[2], px2[2];
        py2[0][0] = (float)h + oy.x;        py2[0][1] = (float)h + oy.y;
        py2[1][0] = (float)h + oy.z;        py2[1][1] = (float)h + oy.w;
        px2[0][0] = (float)(w + 0) + ox.x;  px2[0][1] = (float)(w + 1) + ox.y;
        px2[1][0] = (float)(w + 2) + ox.z;  px2[1][1] = (float)(w + 3) + ox.w;
        int bi[4];
        argmin128(cc4, cc2, py2, px2, bi);
        uchar4 s4 = *(const uchar4*)(semMap + base);
        int sa[4] = {s4.x, s4.y, s4.z, s4.w};
        float pout[4];
#pragma unroll
        for (int q = 0; q < 4; ++q) {
            int sem = sa[q];
            int pan;
            if (sem >= 1 && sem <= 7) {
                pan = anyV ? (clsL[bi[q]] * LABEL_DIVISOR + bi[q] + 1) : 0;
            } else {
                pan = (cntL[sem] >= STUFF_AREA) ? sem * LABEL_DIVISOR : 0;
            }
            pout[q] = (float)pan;
        }
        *(float4*)(out + O_PAN2 + base) = make_float4(pout[0], pout[1], pout[2], pout[3]);
    } else {
        // ---- fused geom3d + pan3d: 4 voxels/thread ----
        int bid3 = blockIdx.x - PAN2_BLOCKS;
        int b = bid3 / (F3D_BLOCKS / B);                 // uniform
        int base = bid3 * 1024 + t * 4;                  // index into [B*G3)
        int v = base - b * G3;
        if (t < K) {
            float cy = cyV[b * K + t], cx = cxV[b * K + t];
            cc4[t] = make_float4(-cy, -cy, -cx, -cx);
            cc2[t] = make_float2(-cy, -cx);
            clsL[t] = clA[b * K + t];
        }
        if (t < C) lcnt[t] = 0;
        __syncthreads();
        // phase A: truncation + 3D argmax + fg counts
        float4 g = *(const float4*)(geom + base);
        float4 o = *(const float4*)(occ + base);
        float go[4];
        go[0] = (o.x <= 0.0f) ? TRUNCATION : g.x;
        go[1] = (o.y <= 0.0f) ? TRUNCATION : g.y;
        go[2] = (o.z <= 0.0f) ? TRUNCATION : g.z;
        go[3] = (o.w <= 0.0f) ? TRUNCATION : g.w;
        *(float4*)(out + O_GEOM + base) = make_float4(go[0], go[1], go[2], go[3]);
        const float* s = sem3in + (size_t)b * C * G3 + v;
        float4 s0 = *(const float4*)s;
        float bv[4] = {s0.x, s0.y, s0.z, s0.w};
        int bc[4] = {0, 0, 0, 0};
#pragma unroll
        for (int c = 1; c < C; ++c) {
            float4 x = *(const float4*)(s + (size_t)c * G3);
            float xa[4] = {x.x, x.y, x.z, x.w};
#pragma unroll
            for (int q = 0; q < 4; ++q)
                if (xa[q] > bv[q]) { bv[q] = xa[q]; bc[q] = c; }
        }
        bool fg[4];
        uint8_t sc4[4];
#pragma unroll
        for (int q = 0; q < 4; ++q) {
            fg[q] = fabsf(go[q]) < TSDF_THRESH;
            if (fg[q]) atomicAdd(&lcnt[bc[q]], 1);
            sc4[q] = (fg[q] && bc[q] >= 8) ? (uint8_t)bc[q] : 0;
        }
        *(uchar4*)(stuffCand + base) = make_uchar4(sc4[0], sc4[1], sc4[2], sc4[3]);
        // phase B: projection + group-min argmin
        float fx = intr[(size_t)b * 9 + 0];              // uniform
        float fy = intr[(size_t)b * 9 + 4];
        float u0 = intr[(size_t)b * 9 + 2];
        float v0 = intr[(size_t)b * 9 + 5];
        int i = v / (G * G);
        int rem = v - i * (G * G);
        int j = rem / G;
        int k0 = rem - j * G;                            // k0..k0+3 same row
        const float* ob = off3 + (size_t)b * 3 * G3 + v;
        float4 o0 = *(const float4*)ob;
        float4 o1 = *(const float4*)(ob + G3);
        float4 o2 = *(const float4*)(ob + 2 * (size_t)G3);
        float oa0[4] = {o0.x, o0.y, o0.z, o0.w};
        float oa1[4] = {o1.x, o1.y, o1.z, o1.w};
        float oa2[4] = {o2.x, o2.y, o2.z, o2.w};
        f32x2 vv2[2], uu2[2];
#pragma unroll
        for (int q = 0; q < 4; ++q) {
            float Xm = ((float)i + oa0[q] + 0.5f) * VOXEL_SIZE - HALF_EXT;
            float Ym = ((float)j + oa1[q] + 0.5f) * VOXEL_SIZE - HALF_EXT;
            float Zr = 0.0f + ((float)(k0 + q) + oa2[q] + 0.5f) * VOXEL_SIZE;
            float Zm = fminf(fmaxf(Zr, 0.1f), DEPTH_MAX);
            uu2[q >> 1][q & 1] = fx * Xm / Zm + u0;
            vv2[q >> 1][q & 1] = fy * Ym / Zm + v0;
        }
        bool anyV = scA[b * K] > CENTER_THRESHOLD;       // uniform
        int bi[4];
        argmin128(cc4, cc2, vv2, uu2, bi);
        float pout[4];
#pragma unroll
        for (int q = 0; q < 4; ++q) {
            int sem = bc[q];
            int pan = 0;
            if (sem >= 1 && sem <= 7) {        // thing: final value now
                pan = anyV ? (clsL[bi[q]] * LABEL_DIVISOR + bi[q] + 1) : 0;
                if (!fg[q]) pan = 0;
            }                                  // stuff: 0 here, k_stuff fills
            pout[q] = (float)pan;
        }
        *(float4*)(out + O_PAN3 + base) = make_float4(pout[0], pout[1], pout[2], pout[3]);
        __syncthreads();
        if (t < C) atomicAdd(&counts3d[b * C + t], lcnt[t]);
    }
}

// Fill stuff voxels (needs completed counts3d). 16 voxels/thread.
__global__ __launch_bounds__(256)
void k_stuff(const uint8_t* __restrict__ stuffCand,
             const int* __restrict__ counts3d,
             float* __restrict__ out) {
    __shared__ int cntL[C];
    constexpr int BPB = F3D_BLOCKS / 4 / B;              // 216 blocks per batch
    int t = threadIdx.x;
    int b = blockIdx.x / BPB;                            // uniform
    if (t < C) cntL[t] = counts3d[b * C + t];
    __syncthreads();
    int base = blockIdx.x * 4096 + t * 16;
    uint4 packed = *(const uint4*)(stuffCand + base);
    uint32_t wds[4] = {packed.x, packed.y, packed.z, packed.w};
#pragma unroll
    for (int wq = 0; wq < 4; ++wq) {
        uint32_t wd = wds[wq];
#pragma unroll
        for (int bq = 0; bq < 4; ++bq) {
            int c = (wd >> (8 * bq)) & 0xFF;
            if (c != 0 && cntL[c] >= STUFF_AREA) {
                out[O_PAN3 + base + wq * 4 + bq] = (float)(c * LABEL_DIVISOR);
            }
        }
    }
}

extern "C" void kernel_launch(void* const* d_in, const int* in_sizes, int n_in,
                              void* d_out, int out_size, void* d_ws, size_t ws_size,
                              hipStream_t stream) {
    const float* semantic2d  = (const float*)d_in[0];
    const float* center2d    = (const float*)d_in[1];
    const float* offset2d    = (const float*)d_in[2];
    const float* geometry    = (const float*)d_in[3];
    const float* occupancy3d = (const float*)d_in[4];
    const float* semantic3d  = (const float*)d_in[5];
    const float* offset3d    = (const float*)d_in[6];
    const float* intrinsic   = (const float*)d_in[7];
    float* out = (float*)d_out;
    char* ws = (char*)d_ws;

    int* candCount = (int*)(ws + 0);      // [B]
    int* counts2d  = (int*)(ws + 16);     // [B*C]
    int* counts3d  = (int*)(ws + 112);    // [B*C]
    float* scA = (float*)(ws + WS_SC);
    int*   clA = (int*)(ws + WS_CL);
    uint8_t* semMap  = (uint8_t*)(ws + WS_SEM2);
    uint8_t* nmsMask = (uint8_t*)(ws + WS_NMS);
    float* candVal = (float*)(ws + WS_CV);
    int*   candIdx = (int*)(ws + WS_CI);
    uint8_t* stuffCand = (uint8_t*)(ws + WS_STUF);
    float* cyV = (float*)(ws + WS_CYV);
    float* cxV = (float*)(ws + WS_CXV);

    hipMemsetAsync(d_ws, 0, 256, stream);

    k_pre2d<<<B * (H / 2), 256, 0, stream>>>(semantic2d, center2d, semMap, nmsMask,
                                             candVal, candIdx, candCount, counts2d);
    k_topk<<<B * TOPK_NB, 256, 0, stream>>>(semMap, nmsMask, candVal, candIdx, candCount,
                                            scA, clA, cyV, cxV, out);
    k_fuse<<<PAN2_BLOCKS + F3D_BLOCKS, 256, 0, stream>>>(
        geometry, occupancy3d, semantic3d, stuffCand, counts3d,
        offset2d, semMap, counts2d, offset3d, intrinsic,
        scA, clA, cyV, cxV, out);
    k_stuff<<<F3D_BLOCKS / 4, 256, 0, stream>>>(stuffCand, counts3d, out);
}